// Round 12
// baseline (369.338 us; speedup 1.0000x reference)
//
#include <hip/hip_runtime.h>
#include <hip/hip_bf16.h>

typedef float f32x4 __attribute__((ext_vector_type(4)));
typedef short s16x8 __attribute__((ext_vector_type(8)));

#define DEVI __device__ __forceinline__

DEVI unsigned short f2bf(float f) {
    return __builtin_bit_cast(unsigned short, __float2bfloat16(f));
}

// Geometry: B=4, C=128, H=W=360, r=9, h=w=40, T=1600 tokens, R2=81 features.
// token t = hh*40+ww, feature k = ch*9+cw, pixel (ch*40+hh, cw*40+ww).
// MFMA mapping (verified R1-R11): D col = lane&15 = B-operand row,
// D row = (lane>>4)*4 + reg = A-operand row; A/B frag: row = lane&15,
// k = (lane>>4)*8 + elem.

// ---------------------------------------------------------------------------
// Kernel 0 (fused prep):
//  blocks 0..63 : Wconv f32 -> bf16
//  blocks 64..99: EAT[j][i] = sum_p WA'[p][i] WB'[p][j]; WCAT[l][q] = Wc[q][l]/bc[q].
__global__ __launch_bounds__(256) void k_prep(
    const float* __restrict__ W, const float* __restrict__ Wa,
    const float* __restrict__ ba, const float* __restrict__ Wb,
    const float* __restrict__ bb, const float* __restrict__ Wc,
    const float* __restrict__ bc, unsigned short* __restrict__ Wbf,
    float* __restrict__ EAT, float* __restrict__ WCAT)
{
    const int tid = threadIdx.x, bid = blockIdx.x;
    if (bid < 64) {
        const int i = bid * 256 + tid;
        Wbf[i] = f2bf(W[i]);
        return;
    }
    const int out = (bid - 64) * 256 + tid; // 0..9215
    const int row = out / 96, col = out % 96;
    float ea = 0.f;
    if (row <= 81 && col <= 81) {
        for (int p = 0; p < 81; ++p) {
            const float wa = (col < 81) ? Wa[p * 81 + col] : ba[p];
            const float wb = (row < 81) ? Wb[p * 81 + row] : bb[p];
            ea += wa * wb;
        }
    }
    EAT[out] = ea;
    float wc = 0.f;
    if (col < 81) {
        if (row < 81) wc = Wc[col * 81 + row];
        else if (row == 81) wc = bc[col];
    }
    WCAT[out] = wc;
}

// ---------------------------------------------------------------------------
// Kernel 1: 1x1 conv GEMM, grid 3240, R7 layout ([n][136], cq-XOR swizzle),
// NEW: K-split software pipeline — stage c<64, barrier, ISSUE loads c>=64,
// MFMA kk=0,1 (reads only c<64) overlapping those loads, stage c>=64,
// barrier, MFMA kk=2,3. Bounce epilogue unchanged.
// XR: bf16 [bo=512][81][1600]
__global__ __launch_bounds__(256, 3) void k_conv(
    const float* __restrict__ x, const unsigned short* __restrict__ Wbf,
    const float* __restrict__ bcv, unsigned short* __restrict__ XR)
{
    __shared__ __align__(16) unsigned short Xs[160 * 136]; // 43.5 KB
    const int tid = threadIdx.x;
    int bid = blockIdx.x;
    const int rb = bid % 10; bid /= 10;
    const int cw = bid % 9;  bid /= 9;
    const int ch = bid % 9;  const int b = bid / 9;
    const int H0 = ch * 40 + rb * 4, w0 = cw * 40;
    const int kfeat = ch * 9 + cw;
    const int t0 = rb * 160;

    const float* xb = x + (size_t)b * 128 * 129600;
    const int lane = tid & 63, wid = tid >> 6;
    const int wm = wid >> 1, wn = wid & 1;  // wm: t-half (80), wn: o-half (64)
    const int lr = lane & 15, lg = lane >> 4;

    // ---- half 0: issue + stage (cq 0..15 = c 0..63), 640 items ----
    float4 va[3][4];
#pragma unroll
    for (int ii = 0; ii < 3; ++ii) {
        const int i = tid + ii * 256;
        if (i < 640) {
            const int cq = i / 40, nq = i % 40;
            const int hh = nq / 10, sub = nq % 10;
            const float* p = xb + (size_t)(cq * 4) * 129600 + (size_t)(H0 + hh) * 360 + w0 + sub * 4;
            va[ii][0] = *reinterpret_cast<const float4*>(p);
            va[ii][1] = *reinterpret_cast<const float4*>(p + 129600);
            va[ii][2] = *reinterpret_cast<const float4*>(p + 2 * 129600);
            va[ii][3] = *reinterpret_cast<const float4*>(p + 3 * 129600);
        }
    }
#pragma unroll
    for (int ii = 0; ii < 3; ++ii) {
        const int i = tid + ii * 256;
        if (i < 640) {
            const int cq = i / 40, nq = i % 40;
            const int hh = nq / 10, sub = nq % 10;
            const int n0 = hh * 40 + sub * 4;
            const int cs = (cq ^ ((((n0 >> 2)) & 7) << 1)) * 4;
            const float4 v0 = va[ii][0], v1 = va[ii][1], v2 = va[ii][2], v3 = va[ii][3];
            ushort4 w0v = { f2bf(v0.x), f2bf(v1.x), f2bf(v2.x), f2bf(v3.x) };
            ushort4 w1v = { f2bf(v0.y), f2bf(v1.y), f2bf(v2.y), f2bf(v3.y) };
            ushort4 w2v = { f2bf(v0.z), f2bf(v1.z), f2bf(v2.z), f2bf(v3.z) };
            ushort4 w3v = { f2bf(v0.w), f2bf(v1.w), f2bf(v2.w), f2bf(v3.w) };
            *reinterpret_cast<ushort4*>(&Xs[(n0 + 0) * 136 + cs]) = w0v;
            *reinterpret_cast<ushort4*>(&Xs[(n0 + 1) * 136 + cs]) = w1v;
            *reinterpret_cast<ushort4*>(&Xs[(n0 + 2) * 136 + cs]) = w2v;
            *reinterpret_cast<ushort4*>(&Xs[(n0 + 3) * 136 + cs]) = w3v;
        }
    }
    __syncthreads(); // half 0 published

    // ---- issue half 1 loads (cq 16..31 = c 64..127) ----
    float4 vb[3][4];
#pragma unroll
    for (int ii = 0; ii < 3; ++ii) {
        const int i = tid + ii * 256;
        if (i < 640) {
            const int cq = 16 + i / 40, nq = i % 40;
            const int hh = nq / 10, sub = nq % 10;
            const float* p = xb + (size_t)(cq * 4) * 129600 + (size_t)(H0 + hh) * 360 + w0 + sub * 4;
            vb[ii][0] = *reinterpret_cast<const float4*>(p);
            vb[ii][1] = *reinterpret_cast<const float4*>(p + 129600);
            vb[ii][2] = *reinterpret_cast<const float4*>(p + 2 * 129600);
            vb[ii][3] = *reinterpret_cast<const float4*>(p + 3 * 129600);
        }
    }

    // ---- MFMA kk = 0,1 (reads c<64 only) — overlaps half-1 loads ----
    f32x4 acc[5][4] = {};
#pragma unroll
    for (int kk = 0; kk < 2; ++kk) {
        s16x8 xa[5], wb[4];
#pragma unroll
        for (int at = 0; at < 5; ++at) {
            const int n = wm * 80 + at * 16 + lr;
            const int cqs = ((kk * 8 + lg * 2) ^ (((n >> 2) & 7) << 1)) * 4;
            xa[at] = *reinterpret_cast<const s16x8*>(&Xs[n * 136 + cqs]);
        }
#pragma unroll
        for (int bt = 0; bt < 4; ++bt)
            wb[bt] = *reinterpret_cast<const s16x8*>(
                Wbf + (wn * 64 + bt * 16 + lr) * 128 + kk * 32 + lg * 8);
#pragma unroll
        for (int at = 0; at < 5; ++at)
#pragma unroll
            for (int bt = 0; bt < 4; ++bt)
                acc[at][bt] = __builtin_amdgcn_mfma_f32_16x16x32_bf16(xa[at], wb[bt], acc[at][bt], 0, 0, 0);
    }

    // ---- stage half 1 (waits its loads; writes c>=64 region only) ----
#pragma unroll
    for (int ii = 0; ii < 3; ++ii) {
        const int i = tid + ii * 256;
        if (i < 640) {
            const int cq = 16 + i / 40, nq = i % 40;
            const int hh = nq / 10, sub = nq % 10;
            const int n0 = hh * 40 + sub * 4;
            const int cs = (cq ^ ((((n0 >> 2)) & 7) << 1)) * 4;
            const float4 v0 = vb[ii][0], v1 = vb[ii][1], v2 = vb[ii][2], v3 = vb[ii][3];
            ushort4 w0v = { f2bf(v0.x), f2bf(v1.x), f2bf(v2.x), f2bf(v3.x) };
            ushort4 w1v = { f2bf(v0.y), f2bf(v1.y), f2bf(v2.y), f2bf(v3.y) };
            ushort4 w2v = { f2bf(v0.z), f2bf(v1.z), f2bf(v2.z), f2bf(v3.z) };
            ushort4 w3v = { f2bf(v0.w), f2bf(v1.w), f2bf(v2.w), f2bf(v3.w) };
            *reinterpret_cast<ushort4*>(&Xs[(n0 + 0) * 136 + cs]) = w0v;
            *reinterpret_cast<ushort4*>(&Xs[(n0 + 1) * 136 + cs]) = w1v;
            *reinterpret_cast<ushort4*>(&Xs[(n0 + 2) * 136 + cs]) = w2v;
            *reinterpret_cast<ushort4*>(&Xs[(n0 + 3) * 136 + cs]) = w3v;
        }
    }
    __syncthreads(); // half 1 published

    // ---- MFMA kk = 2,3 ----
#pragma unroll
    for (int kk = 2; kk < 4; ++kk) {
        s16x8 xa[5], wb[4];
#pragma unroll
        for (int at = 0; at < 5; ++at) {
            const int n = wm * 80 + at * 16 + lr;
            const int cqs = ((kk * 8 + lg * 2) ^ (((n >> 2) & 7) << 1)) * 4;
            xa[at] = *reinterpret_cast<const s16x8*>(&Xs[n * 136 + cqs]);
        }
#pragma unroll
        for (int bt = 0; bt < 4; ++bt)
            wb[bt] = *reinterpret_cast<const s16x8*>(
                Wbf + (wn * 64 + bt * 16 + lr) * 128 + kk * 32 + lg * 8);
#pragma unroll
        for (int at = 0; at < 5; ++at)
#pragma unroll
            for (int bt = 0; bt < 4; ++bt)
                acc[at][bt] = __builtin_amdgcn_mfma_f32_16x16x32_bf16(xa[at], wb[bt], acc[at][bt], 0, 0, 0);
    }

    // ---- epilogue: bounce [o][168] + coalesced store (R7-verified) ----
    __syncthreads();
#pragma unroll
    for (int bt = 0; bt < 4; ++bt) {
        const int o = wn * 64 + bt * 16 + lr;
        const float bias = bcv[o];
#pragma unroll
        for (int at = 0; at < 5; ++at) {
            const int n0 = wm * 80 + at * 16 + lg * 4;
            ushort4 hv = { f2bf(acc[at][bt][0] + bias), f2bf(acc[at][bt][1] + bias),
                           f2bf(acc[at][bt][2] + bias), f2bf(acc[at][bt][3] + bias) };
            *reinterpret_cast<ushort4*>(&Xs[o * 168 + n0]) = hv;
        }
    }
    __syncthreads();
    unsigned short* dstb = XR + (size_t)b * 128 * 129600 + (size_t)kfeat * 1600 + t0;
#pragma unroll
    for (int j = 0; j < 10; ++j) {
        const int item = tid + j * 256;      // 2560 = 128 o x 20 segs
        const int o = item / 20, s2 = item % 20;
        *reinterpret_cast<s16x8*>(dstb + (size_t)o * 129600 + s2 * 8) =
            *reinterpret_cast<const s16x8*>(&Xs[o * 168 + s2 * 8]);
    }
}

// ---------------------------------------------------------------------------
// Kernel 2: partial Gram per (half,bo): G2 = R R^T over 800 tokens (96-pad),
// row 81 = ones so col 81 = partial s.  Grid 1024.
__global__ __launch_bounds__(256) void k_gram(
    const unsigned short* __restrict__ XR, float* __restrict__ G2)
{
    __shared__ __align__(16) unsigned short Rs[96 * 168];
    const int tid = threadIdx.x;
    const int half = blockIdx.x & 1, bo = blockIdx.x >> 1;
    for (int i = 81 * 168 + tid; i < 96 * 168; i += 256)
        Rs[i] = (i < 82 * 168) ? (unsigned short)0x3F80 : (unsigned short)0;
    const unsigned short* Rg = XR + (size_t)bo * 129600;
    const int lane = tid & 63, wid = tid >> 6;
    const int wm = wid >> 1, wn = wid & 1;
    const int lr = lane & 15, lg = lane >> 4;
    f32x4 acc[3][3] = {};
    for (int it = 0; it < 5; ++it) {
        const int t0 = half * 800 + it * 160;
        __syncthreads();
        for (int i = tid; i < 81 * 20; i += 256) {
            const int r = i / 20, g = i % 20;
            *reinterpret_cast<s16x8*>(&Rs[r * 168 + g * 8]) =
                *reinterpret_cast<const s16x8*>(Rg + (size_t)r * 1600 + t0 + g * 8);
        }
        __syncthreads();
#pragma unroll
        for (int kk = 0; kk < 5; ++kk) {
            const int koff = kk * 32 + lg * 8;
            s16x8 af[3], bfr[3];
#pragma unroll
            for (int mt = 0; mt < 3; ++mt)
                af[mt] = *reinterpret_cast<const s16x8*>(&Rs[(wm * 48 + mt * 16 + lr) * 168 + koff]);
#pragma unroll
            for (int nt = 0; nt < 3; ++nt)
                bfr[nt] = *reinterpret_cast<const s16x8*>(&Rs[(wn * 48 + nt * 16 + lr) * 168 + koff]);
#pragma unroll
            for (int mt = 0; mt < 3; ++mt)
#pragma unroll
                for (int nt = 0; nt < 3; ++nt)
                    acc[mt][nt] = __builtin_amdgcn_mfma_f32_16x16x32_bf16(af[mt], bfr[nt], acc[mt][nt], 0, 0, 0);
        }
    }
    float* Gb = G2 + (size_t)(half * 512 + bo) * 9216;
#pragma unroll
    for (int mt = 0; mt < 3; ++mt)
#pragma unroll
        for (int nt = 0; nt < 3; ++nt)
#pragma unroll
            for (int rg = 0; rg < 4; ++rg) {
                const int row = wm * 48 + mt * 16 + lg * 4 + rg;
                const int col = wn * 48 + nt * 16 + lr;
                Gb[row * 96 + col] = acc[mt][nt][rg];
            }
}

// ---------------------------------------------------------------------------
// Kernel 3: per bo: OUT = EA * Ghat * WCA^T / 9. NT[q][k] = OUT[k][q].
__global__ __launch_bounds__(256) void k_small(
    const float* __restrict__ G2, const float* __restrict__ EAT,
    const float* __restrict__ WCAT, unsigned short* __restrict__ NT)
{
    __shared__ float Gs[96 * 98];
    __shared__ float Us[96 * 98];
    const int tid = threadIdx.x;
    const int bo = blockIdx.x;
    const int ty = tid >> 4, tx = tid & 15;
    const int r0 = ty * 6, q0 = tx * 6;

    const float* Gg0 = G2 + (size_t)bo * 9216;
    const float* Gg1 = G2 + (size_t)(512 + bo) * 9216;
    for (int i = tid; i < 96 * 96; i += 256) {
        const int r = i / 96, c = i % 96;
        Gs[r * 98 + c] = Gg0[i] + Gg1[i];
    }
    __syncthreads();

    {
        float acc[6][6] = {};
        for (int l = 0; l <= 81; ++l) {
            float gv[6], wv[6];
#pragma unroll
            for (int a = 0; a < 6; ++a) gv[a] = Gs[l * 98 + r0 + a];
#pragma unroll
            for (int b2 = 0; b2 < 6; ++b2) wv[b2] = WCAT[l * 96 + q0 + b2];
#pragma unroll
            for (int a = 0; a < 6; ++a)
#pragma unroll
                for (int b2 = 0; b2 < 6; ++b2)
                    acc[a][b2] += gv[a] * wv[b2];
        }
#pragma unroll
        for (int a = 0; a < 6; ++a)
#pragma unroll
            for (int b2 = 0; b2 < 6; ++b2)
                Us[(r0 + a) * 98 + q0 + b2] = acc[a][b2];
    }
    __syncthreads();

    float acc[6][6] = {};
    for (int j = 0; j <= 81; ++j) {
        float ev[6], uv[6];
#pragma unroll
        for (int a = 0; a < 6; ++a) ev[a] = EAT[j * 96 + r0 + a];
#pragma unroll
        for (int b2 = 0; b2 < 6; ++b2) uv[b2] = Us[j * 98 + q0 + b2];
#pragma unroll
        for (int a = 0; a < 6; ++a)
#pragma unroll
            for (int b2 = 0; b2 < 6; ++b2)
                acc[a][b2] += ev[a] * uv[b2];
    }
    unsigned short* NTb = NT + (size_t)bo * 9216;
#pragma unroll
    for (int b2 = 0; b2 < 6; ++b2)
#pragma unroll
        for (int a = 0; a < 6; ++a)
            NTb[(q0 + b2) * 96 + (r0 + a)] = f2bf(acc[a][b2] * (1.f / 9.f));
}

// ---------------------------------------------------------------------------
// Kernel 4: y[t][q] = sum_k x~[t][k] N[k][q] + m[q]. Exact R7 structure
// (grid 2560): col8-XOR swizzled [t][128] LDS, register-transpose staging,
// NT frags hoisted, f32x4 stores.
__global__ __launch_bounds__(256) void k_apply(
    const unsigned short* __restrict__ XR, const unsigned short* __restrict__ NT,
    float* __restrict__ out)
{
    __shared__ __align__(16) unsigned short Xs[160 * 128]; // 40 KB
    const int tid = threadIdx.x;
    const int fifth = blockIdx.x % 5, bo = blockIdx.x / 5;
    // init zeros for logical cols 84..95 (col8 = 10 upper half, col8 = 11)
    for (int i = tid; i < 320; i += 256) {
        const int t = i >> 1, h = i & 1;
        const int s = (t >> 3) & 7;
        const ushort4 z = { 0, 0, 0, 0 };
        if (h == 0) {
            *reinterpret_cast<ushort4*>(&Xs[t * 128 + ((10 ^ s) << 3) + 4]) = z;
        } else {
            *reinterpret_cast<ushort4*>(&Xs[t * 128 + ((11 ^ s) << 3)]) = z;
            *reinterpret_cast<ushort4*>(&Xs[t * 128 + ((11 ^ s) << 3) + 4]) = z;
        }
    }
    const int lane = tid & 63, wid = tid >> 6;
    const int wm = wid >> 1, wn = wid & 1;  // wm: t-half (80), wn: q-half (48)
    const int lr = lane & 15, lg = lane >> 4;

    const unsigned short* NTb = NT + (size_t)bo * 9216;
    s16x8 nb[3][3];
#pragma unroll
    for (int qt = 0; qt < 3; ++qt)
#pragma unroll
        for (int kk = 0; kk < 3; ++kk)
            nb[qt][kk] = *reinterpret_cast<const s16x8*>(
                NTb + (wn * 48 + qt * 16 + lr) * 96 + kk * 32 + lg * 8);

    const unsigned short* Rg = XR + (size_t)bo * 129600;
    float* ob = out + (size_t)bo * 129600;

    for (int it = 0; it < 2; ++it) {
        const int t0 = fifth * 320 + it * 160;
        __syncthreads();
        for (int i = tid; i < 420; i += 256) {
            const int kq = i / 20, g = i % 20;
            if (kq < 20) {
                const unsigned short* src = Rg + (size_t)(4 * kq) * 1600 + t0 + g * 8;
                const s16x8 v0 = *reinterpret_cast<const s16x8*>(src);
                const s16x8 v1 = *reinterpret_cast<const s16x8*>(src + 1600);
                const s16x8 v2 = *reinterpret_cast<const s16x8*>(src + 3200);
                const s16x8 v3 = *reinterpret_cast<const s16x8*>(src + 4800);
                const int colb = (((kq >> 1) ^ (g & 7)) << 3) + ((kq & 1) << 2);
#pragma unroll
                for (int e = 0; e < 8; ++e) {
                    const int t = g * 8 + e;
                    ushort4 wv = { (unsigned short)v0[e], (unsigned short)v1[e],
                                   (unsigned short)v2[e], (unsigned short)v3[e] };
                    *reinterpret_cast<ushort4*>(&Xs[t * 128 + colb]) = wv;
                }
            } else {
                const s16x8 v = *reinterpret_cast<const s16x8*>(
                    Rg + (size_t)80 * 1600 + t0 + g * 8);
                const int colb = (10 ^ (g & 7)) << 3;
#pragma unroll
                for (int e = 0; e < 8; ++e) {
                    const int t = g * 8 + e;
                    ushort4 wv = { (unsigned short)v[e], (unsigned short)0x3F80, 0, 0 };
                    *reinterpret_cast<ushort4*>(&Xs[t * 128 + colb]) = wv;
                }
            }
        }
        __syncthreads();
        f32x4 acc[5][3] = {};
#pragma unroll
        for (int kk = 0; kk < 3; ++kk) {
            s16x8 xa[5];
#pragma unroll
            for (int at = 0; at < 5; ++at) {
                const int t = wm * 80 + at * 16 + lr;
                const int s = (t >> 3) & 7;
                xa[at] = *reinterpret_cast<const s16x8*>(
                    &Xs[t * 128 + (((kk * 4 + lg) ^ s) << 3)]);
            }
#pragma unroll
            for (int at = 0; at < 5; ++at)
#pragma unroll
                for (int qt = 0; qt < 3; ++qt)
                    acc[at][qt] = __builtin_amdgcn_mfma_f32_16x16x32_bf16(xa[at], nb[qt][kk], acc[at][qt], 0, 0, 0);
        }
#pragma unroll
        for (int qt = 0; qt < 3; ++qt) {
            const int q = wn * 48 + qt * 16 + lr;
            if (q < 81) {
                const int chq = q / 9, cwq = q % 9;
                float* oq = ob + (size_t)chq * 40 * 360 + cwq * 40;
#pragma unroll
                for (int at = 0; at < 5; ++at) {
                    const int tt = t0 + wm * 80 + at * 16 + lg * 4;
                    const int hh = tt / 40, ww = tt % 40;
                    *reinterpret_cast<f32x4*>(&oq[hh * 360 + ww]) = acc[at][qt];
                }
            }
        }
    }
}

// ---------------------------------------------------------------------------
extern "C" void kernel_launch(void* const* d_in, const int* in_sizes, int n_in,
                              void* d_out, int out_size, void* d_ws, size_t ws_size,
                              hipStream_t stream)
{
    (void)in_sizes; (void)n_in; (void)out_size; (void)ws_size;
    const float* x   = (const float*)d_in[0];
    const float* Wcv = (const float*)d_in[1];
    const float* bcv = (const float*)d_in[2];
    const float* Wa  = (const float*)d_in[3];
    const float* ba  = (const float*)d_in[4];
    const float* Wb  = (const float*)d_in[5];
    const float* bbv = (const float*)d_in[6];
    const float* Wc  = (const float*)d_in[7];
    const float* bc2 = (const float*)d_in[8];
    float* out = (float*)d_out;

    // ws: XR 132,710,400 | G2 37,748,736 | NT 9,437,184 | Wbf 32,768
    //   | EAT 36,864 | WCAT 36,864
    char* w = (char*)d_ws;
    unsigned short* XR = (unsigned short*)w;
    float* G2 = (float*)(w + 132710400ull);
    unsigned short* NT = (unsigned short*)(w + 170459136ull);
    unsigned short* Wbf = (unsigned short*)(w + 179896320ull);
    float* EAT  = (float*)(w + 179929088ull);
    float* WCAT = (float*)(w + 179965952ull);

    k_prep <<<100,  256, 0, stream>>>(Wcv, Wa, ba, Wb, bbv, Wc, bc2, Wbf, EAT, WCAT);
    k_conv <<<3240, 256, 0, stream>>>(x, Wbf, bcv, XR);
    k_gram <<<1024, 256, 0, stream>>>(XR, G2);
    k_small<<<512,  256, 0, stream>>>(G2, EAT, WCAT, NT);
    k_apply<<<2560, 256, 0, stream>>>(XR, NT, out);
}

// Round 13
// 305.461 us; speedup vs baseline: 1.2091x; 1.2091x over previous
//
#include <hip/hip_runtime.h>
#include <hip/hip_bf16.h>

typedef float f32x4 __attribute__((ext_vector_type(4)));
typedef short s16x8 __attribute__((ext_vector_type(8)));

#define DEVI __device__ __forceinline__

DEVI unsigned short f2bf(float f) {
    return __builtin_bit_cast(unsigned short, __float2bfloat16(f));
}

// Geometry: B=4, C=128, H=W=360, r=9, h=w=40, T=1600 tokens, R2=81 features.
// token t = hh*40+ww, feature k = ch*9+cw, pixel (ch*40+hh, cw*40+ww).
// MFMA mapping (verified R1-R12): D col = lane&15 = B-operand row,
// D row = (lane>>4)*4 + reg = A-operand row; A/B frag: row = lane&15,
// k = (lane>>4)*8 + elem.
// R13 = exact revert to R7 (empirical best, 305.5 us).

// ---------------------------------------------------------------------------
// Kernel 0 (fused prep):
//  blocks 0..63 : Wconv f32 -> bf16
//  blocks 64..99: EAT[j][i] = sum_p WA'[p][i] WB'[p][j]; WCAT[l][q] = Wc[q][l]/bc[q].
__global__ __launch_bounds__(256) void k_prep(
    const float* __restrict__ W, const float* __restrict__ Wa,
    const float* __restrict__ ba, const float* __restrict__ Wb,
    const float* __restrict__ bb, const float* __restrict__ Wc,
    const float* __restrict__ bc, unsigned short* __restrict__ Wbf,
    float* __restrict__ EAT, float* __restrict__ WCAT)
{
    const int tid = threadIdx.x, bid = blockIdx.x;
    if (bid < 64) {
        const int i = bid * 256 + tid;
        Wbf[i] = f2bf(W[i]);
        return;
    }
    const int out = (bid - 64) * 256 + tid; // 0..9215
    const int row = out / 96, col = out % 96;
    float ea = 0.f;
    if (row <= 81 && col <= 81) {
        for (int p = 0; p < 81; ++p) {
            const float wa = (col < 81) ? Wa[p * 81 + col] : ba[p];
            const float wb = (row < 81) ? Wb[p * 81 + row] : bb[p];
            ea += wa * wb;
        }
    }
    EAT[out] = ea;
    float wc = 0.f;
    if (col < 81) {
        if (row < 81) wc = Wc[col * 81 + row];
        else if (row == 81) wc = bc[col];
    }
    WCAT[out] = wc;
}

// ---------------------------------------------------------------------------
// Kernel 1: 1x1 conv GEMM, A = x rows (t), B = W rows (o). Staging: batched
// float4 loads -> swizzled [n][136] LDS. Epilogue bounces acc through
// LDS [o][168] then cooperatively stores contiguous 320B per o-row
// (full-line HBM writes, no RFO). XR: bf16 [bo=512][81][1600]
__global__ __launch_bounds__(256, 3) void k_conv(
    const float* __restrict__ x, const unsigned short* __restrict__ Wbf,
    const float* __restrict__ bcv, unsigned short* __restrict__ XR)
{
    __shared__ __align__(16) unsigned short Xs[160 * 136]; // 43.5 KB (reused)
    const int tid = threadIdx.x;
    int bid = blockIdx.x;
    const int rb = bid % 10; bid /= 10;
    const int cw = bid % 9;  bid /= 9;
    const int ch = bid % 9;  const int b = bid / 9;
    const int H0 = ch * 40 + rb * 4, w0 = cw * 40;
    const int kfeat = ch * 9 + cw;
    const int t0 = rb * 160;

    const float* xb = x + (size_t)b * 128 * 129600;
    float4 va[5][4];
#pragma unroll
    for (int ii = 0; ii < 5; ++ii) {
        const int i = tid + ii * 256;
        const int cq = i / 40, nq = i % 40;
        const int hh = nq / 10, sub = nq % 10;
        const float* p = xb + (size_t)(cq * 4) * 129600 + (size_t)(H0 + hh) * 360 + w0 + sub * 4;
        va[ii][0] = *reinterpret_cast<const float4*>(p);
        va[ii][1] = *reinterpret_cast<const float4*>(p + 129600);
        va[ii][2] = *reinterpret_cast<const float4*>(p + 2 * 129600);
        va[ii][3] = *reinterpret_cast<const float4*>(p + 3 * 129600);
    }
#pragma unroll
    for (int ii = 0; ii < 5; ++ii) {
        const int i = tid + ii * 256;
        const int cq = i / 40, nq = i % 40;
        const int hh = nq / 10, sub = nq % 10;
        const int n0 = hh * 40 + sub * 4;
        const int cs = (cq ^ ((((n0 >> 2)) & 7) << 1)) * 4;
        const float4 v0 = va[ii][0], v1 = va[ii][1], v2 = va[ii][2], v3 = va[ii][3];
        ushort4 w0v = { f2bf(v0.x), f2bf(v1.x), f2bf(v2.x), f2bf(v3.x) };
        ushort4 w1v = { f2bf(v0.y), f2bf(v1.y), f2bf(v2.y), f2bf(v3.y) };
        ushort4 w2v = { f2bf(v0.z), f2bf(v1.z), f2bf(v2.z), f2bf(v3.z) };
        ushort4 w3v = { f2bf(v0.w), f2bf(v1.w), f2bf(v2.w), f2bf(v3.w) };
        *reinterpret_cast<ushort4*>(&Xs[(n0 + 0) * 136 + cs]) = w0v;
        *reinterpret_cast<ushort4*>(&Xs[(n0 + 1) * 136 + cs]) = w1v;
        *reinterpret_cast<ushort4*>(&Xs[(n0 + 2) * 136 + cs]) = w2v;
        *reinterpret_cast<ushort4*>(&Xs[(n0 + 3) * 136 + cs]) = w3v;
    }
    __syncthreads();

    const int lane = tid & 63, wid = tid >> 6;
    const int wm = wid >> 1, wn = wid & 1;  // wm: t-half (80), wn: o-half (64)
    const int lr = lane & 15, lg = lane >> 4;

    f32x4 acc[5][4] = {};
#pragma unroll
    for (int kk = 0; kk < 4; ++kk) {
        s16x8 xa[5], wb[4];
#pragma unroll
        for (int at = 0; at < 5; ++at) {
            const int n = wm * 80 + at * 16 + lr;
            const int cqs = ((kk * 8 + lg * 2) ^ (((n >> 2) & 7) << 1)) * 4;
            xa[at] = *reinterpret_cast<const s16x8*>(&Xs[n * 136 + cqs]);
        }
#pragma unroll
        for (int bt = 0; bt < 4; ++bt)
            wb[bt] = *reinterpret_cast<const s16x8*>(
                Wbf + (wn * 64 + bt * 16 + lr) * 128 + kk * 32 + lg * 8);
#pragma unroll
        for (int at = 0; at < 5; ++at)
#pragma unroll
            for (int bt = 0; bt < 4; ++bt)
                acc[at][bt] = __builtin_amdgcn_mfma_f32_16x16x32_bf16(xa[at], wb[bt], acc[at][bt], 0, 0, 0);
    }
    // Epilogue bounce: acc -> LDS [o][168] (2-way banks), then coalesced store.
    __syncthreads();
#pragma unroll
    for (int bt = 0; bt < 4; ++bt) {
        const int o = wn * 64 + bt * 16 + lr;
        const float bias = bcv[o];
#pragma unroll
        for (int at = 0; at < 5; ++at) {
            const int n0 = wm * 80 + at * 16 + lg * 4;
            ushort4 hv = { f2bf(acc[at][bt][0] + bias), f2bf(acc[at][bt][1] + bias),
                           f2bf(acc[at][bt][2] + bias), f2bf(acc[at][bt][3] + bias) };
            *reinterpret_cast<ushort4*>(&Xs[o * 168 + n0]) = hv;
        }
    }
    __syncthreads();
    unsigned short* dstb = XR + (size_t)b * 128 * 129600 + (size_t)kfeat * 1600 + t0;
#pragma unroll
    for (int j = 0; j < 10; ++j) {
        const int item = tid + j * 256;      // 2560 = 128 o x 20 segs
        const int o = item / 20, s2 = item % 20;
        *reinterpret_cast<s16x8*>(dstb + (size_t)o * 129600 + s2 * 8) =
            *reinterpret_cast<const s16x8*>(&Xs[o * 168 + s2 * 8]);
    }
}

// ---------------------------------------------------------------------------
// Kernel 2: partial Gram per (half,bo): G2 = R R^T over 800 tokens (96-pad),
// row 81 = ones so col 81 = partial s.  Grid 1024 (t-split x2 for BW).
__global__ __launch_bounds__(256) void k_gram(
    const unsigned short* __restrict__ XR, float* __restrict__ G2)
{
    __shared__ __align__(16) unsigned short Rs[96 * 168];
    const int tid = threadIdx.x;
    const int half = blockIdx.x & 1, bo = blockIdx.x >> 1;
    for (int i = 81 * 168 + tid; i < 96 * 168; i += 256)
        Rs[i] = (i < 82 * 168) ? (unsigned short)0x3F80 : (unsigned short)0;
    const unsigned short* Rg = XR + (size_t)bo * 129600;
    const int lane = tid & 63, wid = tid >> 6;
    const int wm = wid >> 1, wn = wid & 1;
    const int lr = lane & 15, lg = lane >> 4;
    f32x4 acc[3][3] = {};
    for (int it = 0; it < 5; ++it) {
        const int t0 = half * 800 + it * 160;
        __syncthreads();
        for (int i = tid; i < 81 * 20; i += 256) {
            const int r = i / 20, g = i % 20;
            *reinterpret_cast<s16x8*>(&Rs[r * 168 + g * 8]) =
                *reinterpret_cast<const s16x8*>(Rg + (size_t)r * 1600 + t0 + g * 8);
        }
        __syncthreads();
#pragma unroll
        for (int kk = 0; kk < 5; ++kk) {
            const int koff = kk * 32 + lg * 8;
            s16x8 af[3], bfr[3];
#pragma unroll
            for (int mt = 0; mt < 3; ++mt)
                af[mt] = *reinterpret_cast<const s16x8*>(&Rs[(wm * 48 + mt * 16 + lr) * 168 + koff]);
#pragma unroll
            for (int nt = 0; nt < 3; ++nt)
                bfr[nt] = *reinterpret_cast<const s16x8*>(&Rs[(wn * 48 + nt * 16 + lr) * 168 + koff]);
#pragma unroll
            for (int mt = 0; mt < 3; ++mt)
#pragma unroll
                for (int nt = 0; nt < 3; ++nt)
                    acc[mt][nt] = __builtin_amdgcn_mfma_f32_16x16x32_bf16(af[mt], bfr[nt], acc[mt][nt], 0, 0, 0);
        }
    }
    float* Gb = G2 + (size_t)(half * 512 + bo) * 9216;
#pragma unroll
    for (int mt = 0; mt < 3; ++mt)
#pragma unroll
        for (int nt = 0; nt < 3; ++nt)
#pragma unroll
            for (int rg = 0; rg < 4; ++rg) {
                const int row = wm * 48 + mt * 16 + lg * 4 + rg;
                const int col = wn * 48 + nt * 16 + lr;
                Gb[row * 96 + col] = acc[mt][nt][rg];
            }
}

// ---------------------------------------------------------------------------
// Kernel 3: per bo: OUT = EA * Ghat * WCA^T / 9  (two 82^3 f32 matmuls,
// 6x6 register tiles). NT[q][k] = OUT[k][q].
__global__ __launch_bounds__(256) void k_small(
    const float* __restrict__ G2, const float* __restrict__ EAT,
    const float* __restrict__ WCAT, unsigned short* __restrict__ NT)
{
    __shared__ float Gs[96 * 98];
    __shared__ float Us[96 * 98];
    const int tid = threadIdx.x;
    const int bo = blockIdx.x;
    const int ty = tid >> 4, tx = tid & 15;
    const int r0 = ty * 6, q0 = tx * 6;

    const float* Gg0 = G2 + (size_t)bo * 9216;
    const float* Gg1 = G2 + (size_t)(512 + bo) * 9216;
    for (int i = tid; i < 96 * 96; i += 256) {
        const int r = i / 96, c = i % 96;
        Gs[r * 98 + c] = Gg0[i] + Gg1[i];
    }
    __syncthreads();

    {
        float acc[6][6] = {};
        for (int l = 0; l <= 81; ++l) {
            float gv[6], wv[6];
#pragma unroll
            for (int a = 0; a < 6; ++a) gv[a] = Gs[l * 98 + r0 + a];
#pragma unroll
            for (int b2 = 0; b2 < 6; ++b2) wv[b2] = WCAT[l * 96 + q0 + b2];
#pragma unroll
            for (int a = 0; a < 6; ++a)
#pragma unroll
                for (int b2 = 0; b2 < 6; ++b2)
                    acc[a][b2] += gv[a] * wv[b2];
        }
#pragma unroll
        for (int a = 0; a < 6; ++a)
#pragma unroll
            for (int b2 = 0; b2 < 6; ++b2)
                Us[(r0 + a) * 98 + q0 + b2] = acc[a][b2];
    }
    __syncthreads();

    float acc[6][6] = {};
    for (int j = 0; j <= 81; ++j) {
        float ev[6], uv[6];
#pragma unroll
        for (int a = 0; a < 6; ++a) ev[a] = EAT[j * 96 + r0 + a];
#pragma unroll
        for (int b2 = 0; b2 < 6; ++b2) uv[b2] = Us[j * 98 + q0 + b2];
#pragma unroll
        for (int a = 0; a < 6; ++a)
#pragma unroll
            for (int b2 = 0; b2 < 6; ++b2)
                acc[a][b2] += ev[a] * uv[b2];
    }
    unsigned short* NTb = NT + (size_t)bo * 9216;
#pragma unroll
    for (int b2 = 0; b2 < 6; ++b2)
#pragma unroll
        for (int a = 0; a < 6; ++a)
            NTb[(q0 + b2) * 96 + (r0 + a)] = f2bf(acc[a][b2] * (1.f / 9.f));
}

// ---------------------------------------------------------------------------
// Kernel 4: y[t][q] = sum_k x~[t][k] N[k][q] + m[q].
// Staging: 4-row x 8-t register transpose -> 8 ushort4 LDS writes/item
// into [t][128] with col8-XOR swizzle (k8 ^ ((t>>3)&7)); b128 frag reads
// stay 16B-aligned. kq=20 item fuses x[80] with ones-col 81.
__global__ __launch_bounds__(256) void k_apply(
    const unsigned short* __restrict__ XR, const unsigned short* __restrict__ NT,
    float* __restrict__ out)
{
    __shared__ __align__(16) unsigned short Xs[160 * 128]; // 40 KB
    const int tid = threadIdx.x;
    const int fifth = blockIdx.x % 5, bo = blockIdx.x / 5;
    // init zeros for logical cols 84..95 (col8 = 10 upper half, col8 = 11)
    for (int i = tid; i < 320; i += 256) {
        const int t = i >> 1, h = i & 1;
        const int s = (t >> 3) & 7;
        const ushort4 z = { 0, 0, 0, 0 };
        if (h == 0) {
            *reinterpret_cast<ushort4*>(&Xs[t * 128 + ((10 ^ s) << 3) + 4]) = z;
        } else {
            *reinterpret_cast<ushort4*>(&Xs[t * 128 + ((11 ^ s) << 3)]) = z;
            *reinterpret_cast<ushort4*>(&Xs[t * 128 + ((11 ^ s) << 3) + 4]) = z;
        }
    }
    const int lane = tid & 63, wid = tid >> 6;
    const int wm = wid >> 1, wn = wid & 1;  // wm: t-half (80), wn: q-half (48)
    const int lr = lane & 15, lg = lane >> 4;

    const unsigned short* NTb = NT + (size_t)bo * 9216;
    s16x8 nb[3][3];
#pragma unroll
    for (int qt = 0; qt < 3; ++qt)
#pragma unroll
        for (int kk = 0; kk < 3; ++kk)
            nb[qt][kk] = *reinterpret_cast<const s16x8*>(
                NTb + (wn * 48 + qt * 16 + lr) * 96 + kk * 32 + lg * 8);

    const unsigned short* Rg = XR + (size_t)bo * 129600;
    float* ob = out + (size_t)bo * 129600;

    for (int it = 0; it < 2; ++it) {
        const int t0 = fifth * 320 + it * 160;
        __syncthreads();
        for (int i = tid; i < 420; i += 256) {
            const int kq = i / 20, g = i % 20;
            if (kq < 20) {
                const unsigned short* src = Rg + (size_t)(4 * kq) * 1600 + t0 + g * 8;
                const s16x8 v0 = *reinterpret_cast<const s16x8*>(src);
                const s16x8 v1 = *reinterpret_cast<const s16x8*>(src + 1600);
                const s16x8 v2 = *reinterpret_cast<const s16x8*>(src + 3200);
                const s16x8 v3 = *reinterpret_cast<const s16x8*>(src + 4800);
                const int colb = (((kq >> 1) ^ (g & 7)) << 3) + ((kq & 1) << 2);
#pragma unroll
                for (int e = 0; e < 8; ++e) {
                    const int t = g * 8 + e;
                    ushort4 wv = { (unsigned short)v0[e], (unsigned short)v1[e],
                                   (unsigned short)v2[e], (unsigned short)v3[e] };
                    *reinterpret_cast<ushort4*>(&Xs[t * 128 + colb]) = wv;
                }
            } else {
                const s16x8 v = *reinterpret_cast<const s16x8*>(
                    Rg + (size_t)80 * 1600 + t0 + g * 8);
                const int colb = (10 ^ (g & 7)) << 3;
#pragma unroll
                for (int e = 0; e < 8; ++e) {
                    const int t = g * 8 + e;
                    ushort4 wv = { (unsigned short)v[e], (unsigned short)0x3F80, 0, 0 };
                    *reinterpret_cast<ushort4*>(&Xs[t * 128 + colb]) = wv;
                }
            }
        }
        __syncthreads();
        f32x4 acc[5][3] = {};
#pragma unroll
        for (int kk = 0; kk < 3; ++kk) {
            s16x8 xa[5];
#pragma unroll
            for (int at = 0; at < 5; ++at) {
                const int t = wm * 80 + at * 16 + lr;
                const int s = (t >> 3) & 7;
                xa[at] = *reinterpret_cast<const s16x8*>(
                    &Xs[t * 128 + (((kk * 4 + lg) ^ s) << 3)]);
            }
#pragma unroll
            for (int at = 0; at < 5; ++at)
#pragma unroll
                for (int qt = 0; qt < 3; ++qt)
                    acc[at][qt] = __builtin_amdgcn_mfma_f32_16x16x32_bf16(xa[at], nb[qt][kk], acc[at][qt], 0, 0, 0);
        }
#pragma unroll
        for (int qt = 0; qt < 3; ++qt) {
            const int q = wn * 48 + qt * 16 + lr;
            if (q < 81) {
                const int chq = q / 9, cwq = q % 9;
                float* oq = ob + (size_t)chq * 40 * 360 + cwq * 40;
#pragma unroll
                for (int at = 0; at < 5; ++at) {
                    const int tt = t0 + wm * 80 + at * 16 + lg * 4;
                    const int hh = tt / 40, ww = tt % 40;
                    *reinterpret_cast<f32x4*>(&oq[hh * 360 + ww]) = acc[at][qt];
                }
            }
        }
    }
}

// ---------------------------------------------------------------------------
extern "C" void kernel_launch(void* const* d_in, const int* in_sizes, int n_in,
                              void* d_out, int out_size, void* d_ws, size_t ws_size,
                              hipStream_t stream)
{
    (void)in_sizes; (void)n_in; (void)out_size; (void)ws_size;
    const float* x   = (const float*)d_in[0];
    const float* Wcv = (const float*)d_in[1];
    const float* bcv = (const float*)d_in[2];
    const float* Wa  = (const float*)d_in[3];
    const float* ba  = (const float*)d_in[4];
    const float* Wb  = (const float*)d_in[5];
    const float* bbv = (const float*)d_in[6];
    const float* Wc  = (const float*)d_in[7];
    const float* bc2 = (const float*)d_in[8];
    float* out = (float*)d_out;

    // ws: XR 132,710,400 | G2 37,748,736 | NT 9,437,184 | Wbf 32,768
    //   | EAT 36,864 | WCAT 36,864
    char* w = (char*)d_ws;
    unsigned short* XR = (unsigned short*)w;
    float* G2 = (float*)(w + 132710400ull);
    unsigned short* NT = (unsigned short*)(w + 170459136ull);
    unsigned short* Wbf = (unsigned short*)(w + 179896320ull);
    float* EAT  = (float*)(w + 179929088ull);
    float* WCAT = (float*)(w + 179965952ull);

    k_prep <<<100,  256, 0, stream>>>(Wcv, Wa, ba, Wb, bbv, Wc, bc2, Wbf, EAT, WCAT);
    k_conv <<<3240, 256, 0, stream>>>(x, Wbf, bcv, XR);
    k_gram <<<1024, 256, 0, stream>>>(XR, G2);
    k_small<<<512,  256, 0, stream>>>(G2, EAT, WCAT, NT);
    k_apply<<<2560, 256, 0, stream>>>(XR, NT, out);
}

// Round 14
// 303.580 us; speedup vs baseline: 1.2166x; 1.0062x over previous
//
#include <hip/hip_runtime.h>
#include <hip/hip_bf16.h>

typedef float f32x4 __attribute__((ext_vector_type(4)));
typedef short s16x8 __attribute__((ext_vector_type(8)));

#define DEVI __device__ __forceinline__

DEVI unsigned short f2bf(float f) {
    return __builtin_bit_cast(unsigned short, __float2bfloat16(f));
}

// Geometry: B=4, C=128, H=W=360, r=9, h=w=40, T=1600 tokens, R2=81 features.
// token t = hh*40+ww, feature k = ch*9+cw, pixel (ch*40+hh, cw*40+ww).
// MFMA mapping (verified R1-R13): D col = lane&15 = B-operand row,
// D row = (lane>>4)*4 + reg = A-operand row; A/B frag: row = lane&15,
// k = (lane>>4)*8 + elem.
// R14 = R13 (best, 305.5 us) + k_gram/k_small fused (G2 traffic eliminated).

// ---------------------------------------------------------------------------
// Kernel 0 (fused prep):
//  blocks 0..63 : Wconv f32 -> bf16
//  blocks 64..99: EAT[j][i] = sum_p WA'[p][i] WB'[p][j]; WCAT[l][q] = Wc[q][l]/bc[q].
__global__ __launch_bounds__(256) void k_prep(
    const float* __restrict__ W, const float* __restrict__ Wa,
    const float* __restrict__ ba, const float* __restrict__ Wb,
    const float* __restrict__ bb, const float* __restrict__ Wc,
    const float* __restrict__ bc, unsigned short* __restrict__ Wbf,
    float* __restrict__ EAT, float* __restrict__ WCAT)
{
    const int tid = threadIdx.x, bid = blockIdx.x;
    if (bid < 64) {
        const int i = bid * 256 + tid;
        Wbf[i] = f2bf(W[i]);
        return;
    }
    const int out = (bid - 64) * 256 + tid; // 0..9215
    const int row = out / 96, col = out % 96;
    float ea = 0.f;
    if (row <= 81 && col <= 81) {
        for (int p = 0; p < 81; ++p) {
            const float wa = (col < 81) ? Wa[p * 81 + col] : ba[p];
            const float wb = (row < 81) ? Wb[p * 81 + row] : bb[p];
            ea += wa * wb;
        }
    }
    EAT[out] = ea;
    float wc = 0.f;
    if (col < 81) {
        if (row < 81) wc = Wc[col * 81 + row];
        else if (row == 81) wc = bc[col];
    }
    WCAT[out] = wc;
}

// ---------------------------------------------------------------------------
// Kernel 1: 1x1 conv GEMM (R7-verified). Staging: batched float4 loads ->
// swizzled [n][136] LDS; epilogue bounce [o][168] -> coalesced 320B stores.
// XR: bf16 [bo=512][81][1600]
__global__ __launch_bounds__(256, 3) void k_conv(
    const float* __restrict__ x, const unsigned short* __restrict__ Wbf,
    const float* __restrict__ bcv, unsigned short* __restrict__ XR)
{
    __shared__ __align__(16) unsigned short Xs[160 * 136]; // 43.5 KB (reused)
    const int tid = threadIdx.x;
    int bid = blockIdx.x;
    const int rb = bid % 10; bid /= 10;
    const int cw = bid % 9;  bid /= 9;
    const int ch = bid % 9;  const int b = bid / 9;
    const int H0 = ch * 40 + rb * 4, w0 = cw * 40;
    const int kfeat = ch * 9 + cw;
    const int t0 = rb * 160;

    const float* xb = x + (size_t)b * 128 * 129600;
    float4 va[5][4];
#pragma unroll
    for (int ii = 0; ii < 5; ++ii) {
        const int i = tid + ii * 256;
        const int cq = i / 40, nq = i % 40;
        const int hh = nq / 10, sub = nq % 10;
        const float* p = xb + (size_t)(cq * 4) * 129600 + (size_t)(H0 + hh) * 360 + w0 + sub * 4;
        va[ii][0] = *reinterpret_cast<const float4*>(p);
        va[ii][1] = *reinterpret_cast<const float4*>(p + 129600);
        va[ii][2] = *reinterpret_cast<const float4*>(p + 2 * 129600);
        va[ii][3] = *reinterpret_cast<const float4*>(p + 3 * 129600);
    }
#pragma unroll
    for (int ii = 0; ii < 5; ++ii) {
        const int i = tid + ii * 256;
        const int cq = i / 40, nq = i % 40;
        const int hh = nq / 10, sub = nq % 10;
        const int n0 = hh * 40 + sub * 4;
        const int cs = (cq ^ ((((n0 >> 2)) & 7) << 1)) * 4;
        const float4 v0 = va[ii][0], v1 = va[ii][1], v2 = va[ii][2], v3 = va[ii][3];
        ushort4 w0v = { f2bf(v0.x), f2bf(v1.x), f2bf(v2.x), f2bf(v3.x) };
        ushort4 w1v = { f2bf(v0.y), f2bf(v1.y), f2bf(v2.y), f2bf(v3.y) };
        ushort4 w2v = { f2bf(v0.z), f2bf(v1.z), f2bf(v2.z), f2bf(v3.z) };
        ushort4 w3v = { f2bf(v0.w), f2bf(v1.w), f2bf(v2.w), f2bf(v3.w) };
        *reinterpret_cast<ushort4*>(&Xs[(n0 + 0) * 136 + cs]) = w0v;
        *reinterpret_cast<ushort4*>(&Xs[(n0 + 1) * 136 + cs]) = w1v;
        *reinterpret_cast<ushort4*>(&Xs[(n0 + 2) * 136 + cs]) = w2v;
        *reinterpret_cast<ushort4*>(&Xs[(n0 + 3) * 136 + cs]) = w3v;
    }
    __syncthreads();

    const int lane = tid & 63, wid = tid >> 6;
    const int wm = wid >> 1, wn = wid & 1;  // wm: t-half (80), wn: o-half (64)
    const int lr = lane & 15, lg = lane >> 4;

    f32x4 acc[5][4] = {};
#pragma unroll
    for (int kk = 0; kk < 4; ++kk) {
        s16x8 xa[5], wb[4];
#pragma unroll
        for (int at = 0; at < 5; ++at) {
            const int n = wm * 80 + at * 16 + lr;
            const int cqs = ((kk * 8 + lg * 2) ^ (((n >> 2) & 7) << 1)) * 4;
            xa[at] = *reinterpret_cast<const s16x8*>(&Xs[n * 136 + cqs]);
        }
#pragma unroll
        for (int bt = 0; bt < 4; ++bt)
            wb[bt] = *reinterpret_cast<const s16x8*>(
                Wbf + (wn * 64 + bt * 16 + lr) * 128 + kk * 32 + lg * 8);
#pragma unroll
        for (int at = 0; at < 5; ++at)
#pragma unroll
            for (int bt = 0; bt < 4; ++bt)
                acc[at][bt] = __builtin_amdgcn_mfma_f32_16x16x32_bf16(xa[at], wb[bt], acc[at][bt], 0, 0, 0);
    }
    // Epilogue bounce: acc -> LDS [o][168] (2-way banks), then coalesced store.
    __syncthreads();
#pragma unroll
    for (int bt = 0; bt < 4; ++bt) {
        const int o = wn * 64 + bt * 16 + lr;
        const float bias = bcv[o];
#pragma unroll
        for (int at = 0; at < 5; ++at) {
            const int n0 = wm * 80 + at * 16 + lg * 4;
            ushort4 hv = { f2bf(acc[at][bt][0] + bias), f2bf(acc[at][bt][1] + bias),
                           f2bf(acc[at][bt][2] + bias), f2bf(acc[at][bt][3] + bias) };
            *reinterpret_cast<ushort4*>(&Xs[o * 168 + n0]) = hv;
        }
    }
    __syncthreads();
    unsigned short* dstb = XR + (size_t)b * 128 * 129600 + (size_t)kfeat * 1600 + t0;
#pragma unroll
    for (int j = 0; j < 10; ++j) {
        const int item = tid + j * 256;      // 2560 = 128 o x 20 segs
        const int o = item / 20, s2 = item % 20;
        *reinterpret_cast<s16x8*>(dstb + (size_t)o * 129600 + s2 * 8) =
            *reinterpret_cast<const s16x8*>(&Xs[o * 168 + s2 * 8]);
    }
}

// ---------------------------------------------------------------------------
// Kernel 2+3 FUSED: per bo, (a) Gram Ghat = R R^T over all 1600 tokens
// (96-pad, row 81 = ones -> col 81 = s, corner = 1600) accumulated to LDS Gs,
// (b) OUT = EA * Ghat * WCA^T / 9 via two 82^3 f32 register-tiled matmuls.
// G2 HBM roundtrip eliminated. LDS: Gs 37632 + max(Rs 32256, Us 37632) =
// 75264 B -> 2 blocks/CU. NT[q][k] = OUT[k][q].
__global__ __launch_bounds__(256) void k_gs(
    const unsigned short* __restrict__ XR, const float* __restrict__ EAT,
    const float* __restrict__ WCAT, unsigned short* __restrict__ NT)
{
    __shared__ __align__(16) char smem[37632 + 37632];
    float* Gs = reinterpret_cast<float*>(smem);                       // [96][98]
    unsigned short* Rs = reinterpret_cast<unsigned short*>(smem + 37632); // [96][168]
    float* Us = reinterpret_cast<float*>(smem + 37632);               // [96][98] (aliases Rs)

    const int tid = threadIdx.x;
    const int bo = blockIdx.x;
    // pad rows 81..95 of Rs: row 81 = 1.0 (ones), rest 0.
    for (int i = 81 * 168 + tid; i < 96 * 168; i += 256)
        Rs[i] = (i < 82 * 168) ? (unsigned short)0x3F80 : (unsigned short)0;
    const unsigned short* Rg = XR + (size_t)bo * 129600;
    const int lane = tid & 63, wid = tid >> 6;
    const int wm = wid >> 1, wn = wid & 1;
    const int lr = lane & 15, lg = lane >> 4;

    // --- Gram phase: 10 t-chunks of 160 ---
    f32x4 acc[3][3] = {};
    for (int it = 0; it < 10; ++it) {
        const int t0 = it * 160;
        __syncthreads();
        for (int i = tid; i < 81 * 20; i += 256) {
            const int r = i / 20, g = i % 20;
            *reinterpret_cast<s16x8*>(&Rs[r * 168 + g * 8]) =
                *reinterpret_cast<const s16x8*>(Rg + (size_t)r * 1600 + t0 + g * 8);
        }
        __syncthreads();
#pragma unroll
        for (int kk = 0; kk < 5; ++kk) {
            const int koff = kk * 32 + lg * 8;
            s16x8 af[3], bfr[3];
#pragma unroll
            for (int mt = 0; mt < 3; ++mt)
                af[mt] = *reinterpret_cast<const s16x8*>(&Rs[(wm * 48 + mt * 16 + lr) * 168 + koff]);
#pragma unroll
            for (int nt = 0; nt < 3; ++nt)
                bfr[nt] = *reinterpret_cast<const s16x8*>(&Rs[(wn * 48 + nt * 16 + lr) * 168 + koff]);
#pragma unroll
            for (int mt = 0; mt < 3; ++mt)
#pragma unroll
                for (int nt = 0; nt < 3; ++nt)
                    acc[mt][nt] = __builtin_amdgcn_mfma_f32_16x16x32_bf16(af[mt], bfr[nt], acc[mt][nt], 0, 0, 0);
        }
    }
    // epilogue: acc -> Gs (LDS). Barrier first: all waves' Rs reads complete.
    __syncthreads();
#pragma unroll
    for (int mt = 0; mt < 3; ++mt)
#pragma unroll
        for (int nt = 0; nt < 3; ++nt)
#pragma unroll
            for (int rg = 0; rg < 4; ++rg) {
                const int row = wm * 48 + mt * 16 + lg * 4 + rg;
                const int col = wn * 48 + nt * 16 + lr;
                Gs[row * 98 + col] = acc[mt][nt][rg];
            }
    __syncthreads(); // Gs published; Rs dead (Us may now overwrite)

    // --- small-algebra phase ---
    const int ty = tid >> 4, tx = tid & 15;
    const int r0 = ty * 6, q0 = tx * 6;

    // Matmul A: U[j][q] = sum_{l<=81} Ghat[j][l]*WCA[q][l] = sum_l Gs[l][j]*WCAT[l][q]
    {
        float a2[6][6] = {};
        for (int l = 0; l <= 81; ++l) {
            float gv[6], wv[6];
#pragma unroll
            for (int a = 0; a < 6; ++a) gv[a] = Gs[l * 98 + r0 + a];
#pragma unroll
            for (int b2 = 0; b2 < 6; ++b2) wv[b2] = WCAT[l * 96 + q0 + b2];
#pragma unroll
            for (int a = 0; a < 6; ++a)
#pragma unroll
                for (int b2 = 0; b2 < 6; ++b2)
                    a2[a][b2] += gv[a] * wv[b2];
        }
        __syncthreads(); // ensure everyone past Gs-read deps before Us write? No:
        // Us aliases Rs (dead) — but matmul A reads Gs while writing Us; disjoint
        // regions, safe. This barrier only orders Us writes vs matmul B reads below.
#pragma unroll
        for (int a = 0; a < 6; ++a)
#pragma unroll
            for (int b2 = 0; b2 < 6; ++b2)
                Us[(r0 + a) * 98 + q0 + b2] = a2[a][b2];
    }
    __syncthreads();

    // Matmul B: OUT[i][q] = sum_{j<=81} EAT[j][i]*Us[j][q]; NT[q][i] = OUT/9.
    float a3[6][6] = {};
    for (int j = 0; j <= 81; ++j) {
        float ev[6], uv[6];
#pragma unroll
        for (int a = 0; a < 6; ++a) ev[a] = EAT[j * 96 + r0 + a];
#pragma unroll
        for (int b2 = 0; b2 < 6; ++b2) uv[b2] = Us[j * 98 + q0 + b2];
#pragma unroll
        for (int a = 0; a < 6; ++a)
#pragma unroll
            for (int b2 = 0; b2 < 6; ++b2)
                a3[a][b2] += ev[a] * uv[b2];
    }
    unsigned short* NTb = NT + (size_t)bo * 9216;
#pragma unroll
    for (int b2 = 0; b2 < 6; ++b2)
#pragma unroll
        for (int a = 0; a < 6; ++a)
            NTb[(q0 + b2) * 96 + (r0 + a)] = f2bf(a3[a][b2] * (1.f / 9.f));
}

// ---------------------------------------------------------------------------
// Kernel 4: y[t][q] = sum_k x~[t][k] N[k][q] + m[q]. R7-verified: col8-XOR
// swizzled [t][128] LDS, register-transpose staging, NT frags hoisted,
// f32x4 stores. Grid 2560.
__global__ __launch_bounds__(256) void k_apply(
    const unsigned short* __restrict__ XR, const unsigned short* __restrict__ NT,
    float* __restrict__ out)
{
    __shared__ __align__(16) unsigned short Xs[160 * 128]; // 40 KB
    const int tid = threadIdx.x;
    const int fifth = blockIdx.x % 5, bo = blockIdx.x / 5;
    // init zeros for logical cols 84..95 (col8 = 10 upper half, col8 = 11)
    for (int i = tid; i < 320; i += 256) {
        const int t = i >> 1, h = i & 1;
        const int s = (t >> 3) & 7;
        const ushort4 z = { 0, 0, 0, 0 };
        if (h == 0) {
            *reinterpret_cast<ushort4*>(&Xs[t * 128 + ((10 ^ s) << 3) + 4]) = z;
        } else {
            *reinterpret_cast<ushort4*>(&Xs[t * 128 + ((11 ^ s) << 3)]) = z;
            *reinterpret_cast<ushort4*>(&Xs[t * 128 + ((11 ^ s) << 3) + 4]) = z;
        }
    }
    const int lane = tid & 63, wid = tid >> 6;
    const int wm = wid >> 1, wn = wid & 1;  // wm: t-half (80), wn: q-half (48)
    const int lr = lane & 15, lg = lane >> 4;

    const unsigned short* NTb = NT + (size_t)bo * 9216;
    s16x8 nb[3][3];
#pragma unroll
    for (int qt = 0; qt < 3; ++qt)
#pragma unroll
        for (int kk = 0; kk < 3; ++kk)
            nb[qt][kk] = *reinterpret_cast<const s16x8*>(
                NTb + (wn * 48 + qt * 16 + lr) * 96 + kk * 32 + lg * 8);

    const unsigned short* Rg = XR + (size_t)bo * 129600;
    float* ob = out + (size_t)bo * 129600;

    for (int it = 0; it < 2; ++it) {
        const int t0 = fifth * 320 + it * 160;
        __syncthreads();
        for (int i = tid; i < 420; i += 256) {
            const int kq = i / 20, g = i % 20;
            if (kq < 20) {
                const unsigned short* src = Rg + (size_t)(4 * kq) * 1600 + t0 + g * 8;
                const s16x8 v0 = *reinterpret_cast<const s16x8*>(src);
                const s16x8 v1 = *reinterpret_cast<const s16x8*>(src + 1600);
                const s16x8 v2 = *reinterpret_cast<const s16x8*>(src + 3200);
                const s16x8 v3 = *reinterpret_cast<const s16x8*>(src + 4800);
                const int colb = (((kq >> 1) ^ (g & 7)) << 3) + ((kq & 1) << 2);
#pragma unroll
                for (int e = 0; e < 8; ++e) {
                    const int t = g * 8 + e;
                    ushort4 wv = { (unsigned short)v0[e], (unsigned short)v1[e],
                                   (unsigned short)v2[e], (unsigned short)v3[e] };
                    *reinterpret_cast<ushort4*>(&Xs[t * 128 + colb]) = wv;
                }
            } else {
                const s16x8 v = *reinterpret_cast<const s16x8*>(
                    Rg + (size_t)80 * 1600 + t0 + g * 8);
                const int colb = (10 ^ (g & 7)) << 3;
#pragma unroll
                for (int e = 0; e < 8; ++e) {
                    const int t = g * 8 + e;
                    ushort4 wv = { (unsigned short)v[e], (unsigned short)0x3F80, 0, 0 };
                    *reinterpret_cast<ushort4*>(&Xs[t * 128 + colb]) = wv;
                }
            }
        }
        __syncthreads();
        f32x4 acc[5][3] = {};
#pragma unroll
        for (int kk = 0; kk < 3; ++kk) {
            s16x8 xa[5];
#pragma unroll
            for (int at = 0; at < 5; ++at) {
                const int t = wm * 80 + at * 16 + lr;
                const int s = (t >> 3) & 7;
                xa[at] = *reinterpret_cast<const s16x8*>(
                    &Xs[t * 128 + (((kk * 4 + lg) ^ s) << 3)]);
            }
#pragma unroll
            for (int at = 0; at < 5; ++at)
#pragma unroll
                for (int qt = 0; qt < 3; ++qt)
                    acc[at][qt] = __builtin_amdgcn_mfma_f32_16x16x32_bf16(xa[at], nb[qt][kk], acc[at][qt], 0, 0, 0);
        }
#pragma unroll
        for (int qt = 0; qt < 3; ++qt) {
            const int q = wn * 48 + qt * 16 + lr;
            if (q < 81) {
                const int chq = q / 9, cwq = q % 9;
                float* oq = ob + (size_t)chq * 40 * 360 + cwq * 40;
#pragma unroll
                for (int at = 0; at < 5; ++at) {
                    const int tt = t0 + wm * 80 + at * 16 + lg * 4;
                    const int hh = tt / 40, ww = tt % 40;
                    *reinterpret_cast<f32x4*>(&oq[hh * 360 + ww]) = acc[at][qt];
                }
            }
        }
    }
}

// ---------------------------------------------------------------------------
extern "C" void kernel_launch(void* const* d_in, const int* in_sizes, int n_in,
                              void* d_out, int out_size, void* d_ws, size_t ws_size,
                              hipStream_t stream)
{
    (void)in_sizes; (void)n_in; (void)out_size; (void)ws_size;
    const float* x   = (const float*)d_in[0];
    const float* Wcv = (const float*)d_in[1];
    const float* bcv = (const float*)d_in[2];
    const float* Wa  = (const float*)d_in[3];
    const float* ba  = (const float*)d_in[4];
    const float* Wb  = (const float*)d_in[5];
    const float* bbv = (const float*)d_in[6];
    const float* Wc  = (const float*)d_in[7];
    const float* bc2 = (const float*)d_in[8];
    float* out = (float*)d_out;

    // ws: XR 132,710,400 | (G2 region unused) | NT 9,437,184 | Wbf 32,768
    //   | EAT 36,864 | WCAT 36,864
    char* w = (char*)d_ws;
    unsigned short* XR = (unsigned short*)w;
    unsigned short* NT = (unsigned short*)(w + 170459136ull);
    unsigned short* Wbf = (unsigned short*)(w + 179896320ull);
    float* EAT  = (float*)(w + 179929088ull);
    float* WCAT = (float*)(w + 179965952ull);

    k_prep <<<100,  256, 0, stream>>>(Wcv, Wa, ba, Wb, bbv, Wc, bc2, Wbf, EAT, WCAT);
    k_conv <<<3240, 256, 0, stream>>>(x, Wbf, bcv, XR);
    k_gs   <<<512,  256, 0, stream>>>(XR, EAT, WCAT, NT);
    k_apply<<<2560, 256, 0, stream>>>(XR, NT, out);
}

// Round 15
// 301.195 us; speedup vs baseline: 1.2262x; 1.0079x over previous
//
#include <hip/hip_runtime.h>
#include <hip/hip_bf16.h>

typedef float f32x4 __attribute__((ext_vector_type(4)));
typedef short s16x8 __attribute__((ext_vector_type(8)));

#define DEVI __device__ __forceinline__

DEVI unsigned short f2bf(float f) {
    return __builtin_bit_cast(unsigned short, __float2bfloat16(f));
}

// Geometry: B=4, C=128, H=W=360, r=9, h=w=40, T=1600 tokens, R2=81 features.
// token t = hh*40+ww, feature k = ch*9+cw, pixel (ch*40+hh, cw*40+ww).
// MFMA mapping (verified R1-R14): D col = lane&15 = B-operand row,
// D row = (lane>>4)*4 + reg = A-operand row; A/B frag: row = lane&15,
// k = (lane>>4)*8 + elem.
// R15 = R14 (best, 303.6 us) + k_apply 10-way t-split (grid 5120).

// ---------------------------------------------------------------------------
// Kernel 0 (fused prep):
//  blocks 0..63 : Wconv f32 -> bf16
//  blocks 64..99: EAT[j][i] = sum_p WA'[p][i] WB'[p][j]; WCAT[l][q] = Wc[q][l]/bc[q].
__global__ __launch_bounds__(256) void k_prep(
    const float* __restrict__ W, const float* __restrict__ Wa,
    const float* __restrict__ ba, const float* __restrict__ Wb,
    const float* __restrict__ bb, const float* __restrict__ Wc,
    const float* __restrict__ bc, unsigned short* __restrict__ Wbf,
    float* __restrict__ EAT, float* __restrict__ WCAT)
{
    const int tid = threadIdx.x, bid = blockIdx.x;
    if (bid < 64) {
        const int i = bid * 256 + tid;
        Wbf[i] = f2bf(W[i]);
        return;
    }
    const int out = (bid - 64) * 256 + tid; // 0..9215
    const int row = out / 96, col = out % 96;
    float ea = 0.f;
    if (row <= 81 && col <= 81) {
        for (int p = 0; p < 81; ++p) {
            const float wa = (col < 81) ? Wa[p * 81 + col] : ba[p];
            const float wb = (row < 81) ? Wb[p * 81 + row] : bb[p];
            ea += wa * wb;
        }
    }
    EAT[out] = ea;
    float wc = 0.f;
    if (col < 81) {
        if (row < 81) wc = Wc[col * 81 + row];
        else if (row == 81) wc = bc[col];
    }
    WCAT[out] = wc;
}

// ---------------------------------------------------------------------------
// Kernel 1: 1x1 conv GEMM (R7-verified). Staging: batched float4 loads ->
// swizzled [n][136] LDS; epilogue bounce [o][168] -> coalesced 320B stores.
// XR: bf16 [bo=512][81][1600]
__global__ __launch_bounds__(256, 3) void k_conv(
    const float* __restrict__ x, const unsigned short* __restrict__ Wbf,
    const float* __restrict__ bcv, unsigned short* __restrict__ XR)
{
    __shared__ __align__(16) unsigned short Xs[160 * 136]; // 43.5 KB (reused)
    const int tid = threadIdx.x;
    int bid = blockIdx.x;
    const int rb = bid % 10; bid /= 10;
    const int cw = bid % 9;  bid /= 9;
    const int ch = bid % 9;  const int b = bid / 9;
    const int H0 = ch * 40 + rb * 4, w0 = cw * 40;
    const int kfeat = ch * 9 + cw;
    const int t0 = rb * 160;

    const float* xb = x + (size_t)b * 128 * 129600;
    float4 va[5][4];
#pragma unroll
    for (int ii = 0; ii < 5; ++ii) {
        const int i = tid + ii * 256;
        const int cq = i / 40, nq = i % 40;
        const int hh = nq / 10, sub = nq % 10;
        const float* p = xb + (size_t)(cq * 4) * 129600 + (size_t)(H0 + hh) * 360 + w0 + sub * 4;
        va[ii][0] = *reinterpret_cast<const float4*>(p);
        va[ii][1] = *reinterpret_cast<const float4*>(p + 129600);
        va[ii][2] = *reinterpret_cast<const float4*>(p + 2 * 129600);
        va[ii][3] = *reinterpret_cast<const float4*>(p + 3 * 129600);
    }
#pragma unroll
    for (int ii = 0; ii < 5; ++ii) {
        const int i = tid + ii * 256;
        const int cq = i / 40, nq = i % 40;
        const int hh = nq / 10, sub = nq % 10;
        const int n0 = hh * 40 + sub * 4;
        const int cs = (cq ^ ((((n0 >> 2)) & 7) << 1)) * 4;
        const float4 v0 = va[ii][0], v1 = va[ii][1], v2 = va[ii][2], v3 = va[ii][3];
        ushort4 w0v = { f2bf(v0.x), f2bf(v1.x), f2bf(v2.x), f2bf(v3.x) };
        ushort4 w1v = { f2bf(v0.y), f2bf(v1.y), f2bf(v2.y), f2bf(v3.y) };
        ushort4 w2v = { f2bf(v0.z), f2bf(v1.z), f2bf(v2.z), f2bf(v3.z) };
        ushort4 w3v = { f2bf(v0.w), f2bf(v1.w), f2bf(v2.w), f2bf(v3.w) };
        *reinterpret_cast<ushort4*>(&Xs[(n0 + 0) * 136 + cs]) = w0v;
        *reinterpret_cast<ushort4*>(&Xs[(n0 + 1) * 136 + cs]) = w1v;
        *reinterpret_cast<ushort4*>(&Xs[(n0 + 2) * 136 + cs]) = w2v;
        *reinterpret_cast<ushort4*>(&Xs[(n0 + 3) * 136 + cs]) = w3v;
    }
    __syncthreads();

    const int lane = tid & 63, wid = tid >> 6;
    const int wm = wid >> 1, wn = wid & 1;  // wm: t-half (80), wn: o-half (64)
    const int lr = lane & 15, lg = lane >> 4;

    f32x4 acc[5][4] = {};
#pragma unroll
    for (int kk = 0; kk < 4; ++kk) {
        s16x8 xa[5], wb[4];
#pragma unroll
        for (int at = 0; at < 5; ++at) {
            const int n = wm * 80 + at * 16 + lr;
            const int cqs = ((kk * 8 + lg * 2) ^ (((n >> 2) & 7) << 1)) * 4;
            xa[at] = *reinterpret_cast<const s16x8*>(&Xs[n * 136 + cqs]);
        }
#pragma unroll
        for (int bt = 0; bt < 4; ++bt)
            wb[bt] = *reinterpret_cast<const s16x8*>(
                Wbf + (wn * 64 + bt * 16 + lr) * 128 + kk * 32 + lg * 8);
#pragma unroll
        for (int at = 0; at < 5; ++at)
#pragma unroll
            for (int bt = 0; bt < 4; ++bt)
                acc[at][bt] = __builtin_amdgcn_mfma_f32_16x16x32_bf16(xa[at], wb[bt], acc[at][bt], 0, 0, 0);
    }
    // Epilogue bounce: acc -> LDS [o][168] (2-way banks), then coalesced store.
    __syncthreads();
#pragma unroll
    for (int bt = 0; bt < 4; ++bt) {
        const int o = wn * 64 + bt * 16 + lr;
        const float bias = bcv[o];
#pragma unroll
        for (int at = 0; at < 5; ++at) {
            const int n0 = wm * 80 + at * 16 + lg * 4;
            ushort4 hv = { f2bf(acc[at][bt][0] + bias), f2bf(acc[at][bt][1] + bias),
                           f2bf(acc[at][bt][2] + bias), f2bf(acc[at][bt][3] + bias) };
            *reinterpret_cast<ushort4*>(&Xs[o * 168 + n0]) = hv;
        }
    }
    __syncthreads();
    unsigned short* dstb = XR + (size_t)b * 128 * 129600 + (size_t)kfeat * 1600 + t0;
#pragma unroll
    for (int j = 0; j < 10; ++j) {
        const int item = tid + j * 256;      // 2560 = 128 o x 20 segs
        const int o = item / 20, s2 = item % 20;
        *reinterpret_cast<s16x8*>(dstb + (size_t)o * 129600 + s2 * 8) =
            *reinterpret_cast<const s16x8*>(&Xs[o * 168 + s2 * 8]);
    }
}

// ---------------------------------------------------------------------------
// Kernel 2+3 FUSED (R14-verified): per bo, Gram Ghat = R R^T (96-pad, row 81
// = ones) accumulated in LDS, then OUT = EA * Ghat * WCA^T / 9 via two 82^3
// f32 register-tiled matmuls. NT[q][k] = OUT[k][q].
__global__ __launch_bounds__(256) void k_gs(
    const unsigned short* __restrict__ XR, const float* __restrict__ EAT,
    const float* __restrict__ WCAT, unsigned short* __restrict__ NT)
{
    __shared__ __align__(16) char smem[37632 + 37632];
    float* Gs = reinterpret_cast<float*>(smem);                       // [96][98]
    unsigned short* Rs = reinterpret_cast<unsigned short*>(smem + 37632); // [96][168]
    float* Us = reinterpret_cast<float*>(smem + 37632);               // [96][98] (aliases Rs)

    const int tid = threadIdx.x;
    const int bo = blockIdx.x;
    for (int i = 81 * 168 + tid; i < 96 * 168; i += 256)
        Rs[i] = (i < 82 * 168) ? (unsigned short)0x3F80 : (unsigned short)0;
    const unsigned short* Rg = XR + (size_t)bo * 129600;
    const int lane = tid & 63, wid = tid >> 6;
    const int wm = wid >> 1, wn = wid & 1;
    const int lr = lane & 15, lg = lane >> 4;

    f32x4 acc[3][3] = {};
    for (int it = 0; it < 10; ++it) {
        const int t0 = it * 160;
        __syncthreads();
        for (int i = tid; i < 81 * 20; i += 256) {
            const int r = i / 20, g = i % 20;
            *reinterpret_cast<s16x8*>(&Rs[r * 168 + g * 8]) =
                *reinterpret_cast<const s16x8*>(Rg + (size_t)r * 1600 + t0 + g * 8);
        }
        __syncthreads();
#pragma unroll
        for (int kk = 0; kk < 5; ++kk) {
            const int koff = kk * 32 + lg * 8;
            s16x8 af[3], bfr[3];
#pragma unroll
            for (int mt = 0; mt < 3; ++mt)
                af[mt] = *reinterpret_cast<const s16x8*>(&Rs[(wm * 48 + mt * 16 + lr) * 168 + koff]);
#pragma unroll
            for (int nt = 0; nt < 3; ++nt)
                bfr[nt] = *reinterpret_cast<const s16x8*>(&Rs[(wn * 48 + nt * 16 + lr) * 168 + koff]);
#pragma unroll
            for (int mt = 0; mt < 3; ++mt)
#pragma unroll
                for (int nt = 0; nt < 3; ++nt)
                    acc[mt][nt] = __builtin_amdgcn_mfma_f32_16x16x32_bf16(af[mt], bfr[nt], acc[mt][nt], 0, 0, 0);
        }
    }
    __syncthreads();
#pragma unroll
    for (int mt = 0; mt < 3; ++mt)
#pragma unroll
        for (int nt = 0; nt < 3; ++nt)
#pragma unroll
            for (int rg = 0; rg < 4; ++rg) {
                const int row = wm * 48 + mt * 16 + lg * 4 + rg;
                const int col = wn * 48 + nt * 16 + lr;
                Gs[row * 98 + col] = acc[mt][nt][rg];
            }
    __syncthreads(); // Gs published; Rs dead (Us may now overwrite)

    const int ty = tid >> 4, tx = tid & 15;
    const int r0 = ty * 6, q0 = tx * 6;

    {
        float a2[6][6] = {};
        for (int l = 0; l <= 81; ++l) {
            float gv[6], wv[6];
#pragma unroll
            for (int a = 0; a < 6; ++a) gv[a] = Gs[l * 98 + r0 + a];
#pragma unroll
            for (int b2 = 0; b2 < 6; ++b2) wv[b2] = WCAT[l * 96 + q0 + b2];
#pragma unroll
            for (int a = 0; a < 6; ++a)
#pragma unroll
                for (int b2 = 0; b2 < 6; ++b2)
                    a2[a][b2] += gv[a] * wv[b2];
        }
        __syncthreads();
#pragma unroll
        for (int a = 0; a < 6; ++a)
#pragma unroll
            for (int b2 = 0; b2 < 6; ++b2)
                Us[(r0 + a) * 98 + q0 + b2] = a2[a][b2];
    }
    __syncthreads();

    float a3[6][6] = {};
    for (int j = 0; j <= 81; ++j) {
        float ev[6], uv[6];
#pragma unroll
        for (int a = 0; a < 6; ++a) ev[a] = EAT[j * 96 + r0 + a];
#pragma unroll
        for (int b2 = 0; b2 < 6; ++b2) uv[b2] = Us[j * 98 + q0 + b2];
#pragma unroll
        for (int a = 0; a < 6; ++a)
#pragma unroll
            for (int b2 = 0; b2 < 6; ++b2)
                a3[a][b2] += ev[a] * uv[b2];
    }
    unsigned short* NTb = NT + (size_t)bo * 9216;
#pragma unroll
    for (int b2 = 0; b2 < 6; ++b2)
#pragma unroll
        for (int a = 0; a < 6; ++a)
            NTb[(q0 + b2) * 96 + (r0 + a)] = f2bf(a3[a][b2] * (1.f / 9.f));
}

// ---------------------------------------------------------------------------
// Kernel 4: y[t][q] = sum_k x~[t][k] N[k][q] + m[q]. R7-verified body, NEW:
// 10-way t-split (ONE 160-token chunk per block, grid 5120) for phase
// diversity across co-resident blocks. col8-XOR swizzled [t][128] LDS,
// register-transpose staging, f32x4 stores.
__global__ __launch_bounds__(256) void k_apply(
    const unsigned short* __restrict__ XR, const unsigned short* __restrict__ NT,
    float* __restrict__ out)
{
    __shared__ __align__(16) unsigned short Xs[160 * 128]; // 40 KB
    const int tid = threadIdx.x;
    const int tenth = blockIdx.x % 10, bo = blockIdx.x / 10;
    const int t0 = tenth * 160;
    // init zeros for logical cols 84..95 (col8 = 10 upper half, col8 = 11)
    for (int i = tid; i < 320; i += 256) {
        const int t = i >> 1, h = i & 1;
        const int s = (t >> 3) & 7;
        const ushort4 z = { 0, 0, 0, 0 };
        if (h == 0) {
            *reinterpret_cast<ushort4*>(&Xs[t * 128 + ((10 ^ s) << 3) + 4]) = z;
        } else {
            *reinterpret_cast<ushort4*>(&Xs[t * 128 + ((11 ^ s) << 3)]) = z;
            *reinterpret_cast<ushort4*>(&Xs[t * 128 + ((11 ^ s) << 3) + 4]) = z;
        }
    }
    const int lane = tid & 63, wid = tid >> 6;
    const int wm = wid >> 1, wn = wid & 1;  // wm: t-half (80), wn: q-half (48)
    const int lr = lane & 15, lg = lane >> 4;

    const unsigned short* NTb = NT + (size_t)bo * 9216;
    s16x8 nb[3][3];
#pragma unroll
    for (int qt = 0; qt < 3; ++qt)
#pragma unroll
        for (int kk = 0; kk < 3; ++kk)
            nb[qt][kk] = *reinterpret_cast<const s16x8*>(
                NTb + (wn * 48 + qt * 16 + lr) * 96 + kk * 32 + lg * 8);

    const unsigned short* Rg = XR + (size_t)bo * 129600;
    float* ob = out + (size_t)bo * 129600;

    // stage transposed chunk
    for (int i = tid; i < 420; i += 256) {
        const int kq = i / 20, g = i % 20;
        if (kq < 20) {
            const unsigned short* src = Rg + (size_t)(4 * kq) * 1600 + t0 + g * 8;
            const s16x8 v0 = *reinterpret_cast<const s16x8*>(src);
            const s16x8 v1 = *reinterpret_cast<const s16x8*>(src + 1600);
            const s16x8 v2 = *reinterpret_cast<const s16x8*>(src + 3200);
            const s16x8 v3 = *reinterpret_cast<const s16x8*>(src + 4800);
            const int colb = (((kq >> 1) ^ (g & 7)) << 3) + ((kq & 1) << 2);
#pragma unroll
            for (int e = 0; e < 8; ++e) {
                const int t = g * 8 + e;
                ushort4 wv = { (unsigned short)v0[e], (unsigned short)v1[e],
                               (unsigned short)v2[e], (unsigned short)v3[e] };
                *reinterpret_cast<ushort4*>(&Xs[t * 128 + colb]) = wv;
            }
        } else {
            const s16x8 v = *reinterpret_cast<const s16x8*>(
                Rg + (size_t)80 * 1600 + t0 + g * 8);
            const int colb = (10 ^ (g & 7)) << 3;
#pragma unroll
            for (int e = 0; e < 8; ++e) {
                const int t = g * 8 + e;
                ushort4 wv = { (unsigned short)v[e], (unsigned short)0x3F80, 0, 0 };
                *reinterpret_cast<ushort4*>(&Xs[t * 128 + colb]) = wv;
            }
        }
    }
    __syncthreads();
    f32x4 acc[5][3] = {};
#pragma unroll
    for (int kk = 0; kk < 3; ++kk) {
        s16x8 xa[5];
#pragma unroll
        for (int at = 0; at < 5; ++at) {
            const int t = wm * 80 + at * 16 + lr;
            const int s = (t >> 3) & 7;
            xa[at] = *reinterpret_cast<const s16x8*>(
                &Xs[t * 128 + (((kk * 4 + lg) ^ s) << 3)]);
        }
#pragma unroll
        for (int at = 0; at < 5; ++at)
#pragma unroll
            for (int qt = 0; qt < 3; ++qt)
                acc[at][qt] = __builtin_amdgcn_mfma_f32_16x16x32_bf16(xa[at], nb[qt][kk], acc[at][qt], 0, 0, 0);
    }
#pragma unroll
    for (int qt = 0; qt < 3; ++qt) {
        const int q = wn * 48 + qt * 16 + lr;
        if (q < 81) {
            const int chq = q / 9, cwq = q % 9;
            float* oq = ob + (size_t)chq * 40 * 360 + cwq * 40;
#pragma unroll
            for (int at = 0; at < 5; ++at) {
                const int tt = t0 + wm * 80 + at * 16 + lg * 4;
                const int hh = tt / 40, ww = tt % 40;
                *reinterpret_cast<f32x4*>(&oq[hh * 360 + ww]) = acc[at][qt];
            }
        }
    }
}

// ---------------------------------------------------------------------------
extern "C" void kernel_launch(void* const* d_in, const int* in_sizes, int n_in,
                              void* d_out, int out_size, void* d_ws, size_t ws_size,
                              hipStream_t stream)
{
    (void)in_sizes; (void)n_in; (void)out_size; (void)ws_size;
    const float* x   = (const float*)d_in[0];
    const float* Wcv = (const float*)d_in[1];
    const float* bcv = (const float*)d_in[2];
    const float* Wa  = (const float*)d_in[3];
    const float* ba  = (const float*)d_in[4];
    const float* Wb  = (const float*)d_in[5];
    const float* bbv = (const float*)d_in[6];
    const float* Wc  = (const float*)d_in[7];
    const float* bc2 = (const float*)d_in[8];
    float* out = (float*)d_out;

    // ws: XR 132,710,400 | (G2 region unused) | NT 9,437,184 | Wbf 32,768
    //   | EAT 36,864 | WCAT 36,864
    char* w = (char*)d_ws;
    unsigned short* XR = (unsigned short*)w;
    unsigned short* NT = (unsigned short*)(w + 170459136ull);
    unsigned short* Wbf = (unsigned short*)(w + 179896320ull);
    float* EAT  = (float*)(w + 179929088ull);
    float* WCAT = (float*)(w + 179965952ull);

    k_prep <<<100,  256, 0, stream>>>(Wcv, Wa, ba, Wb, bbv, Wc, bc2, Wbf, EAT, WCAT);
    k_conv <<<3240, 256, 0, stream>>>(x, Wbf, bcv, XR);
    k_gs   <<<512,  256, 0, stream>>>(XR, EAT, WCAT, NT);
    k_apply<<<5120, 256, 0, stream>>>(XR, NT, out);
}